// Round 5
// baseline (737.261 us; speedup 1.0000x reference)
//
#include <hip/hip_runtime.h>
#include <stdint.h>

// Problem: BahdanauAttention  H=512, L=2, B=64, T=2048
// scores[t,b] = Wo . tanh( enc[t,b,:] @ We^T + comb[b,:] )   (bo dropped: softmax-invariant)
// comb[b,:]   = mean_l(hidden[l,b,:]) @ Wh^T + bh + be
// out[b,t]    = masked softmax over t < enc_len[b]
//
// R5: barrier-free streaming GEMM. N split into 4 col-quarters (tanh/Wo-dot
// commute over o-subsets; partials combined via atomicAdd). Block stages its
// quarter's FULL-K B panel (128 cols x 512 K bf16 = 128 KB LDS) once; 8 waves
// then free-run: A global->VGPR directly as 32x32x16 MFMA frags (no LDS, no
// barriers), 4-deep reg prefetch. Quarter-blocks of same M-chunk share an XCD.
//
// Workspace (1,179,648 B, same as proven):
//   [0, 512K)     : We packed bf16, 4 quarter-panels of 128KB (LDS image order)
//   [512K, 640K)  : comb f32 [64][512]
//   [640K, 1152K) : scores f32 [64][2048]  (zeroed each call by prep_pack)

typedef __attribute__((ext_vector_type(4))) float f32x4;
typedef __attribute__((ext_vector_type(16))) float f32x16;
typedef __attribute__((ext_vector_type(8))) __bf16 bf16x8;
typedef __attribute__((ext_vector_type(8))) unsigned short u16x8;

#define AS3 __attribute__((address_space(3)))
#define AS1 __attribute__((address_space(1)))

__device__ __forceinline__ float fast_tanh(float x) {
  float t = __expf(-2.0f * __builtin_fabsf(x));
  float r = (1.0f - t) * __builtin_amdgcn_rcpf(1.0f + t);
  return __builtin_copysignf(r, x);
}

// ---------------- prep 1: comb[b,o] = mean_l hidden @ Wh^T + bh + be ----------
__global__ void prep_comb_kernel(const float* __restrict__ hidden,
                                 const float* __restrict__ Wh,
                                 const float* __restrict__ bh,
                                 const float* __restrict__ be,
                                 float* __restrict__ comb) {
  __shared__ float hb[512];
  const int b = blockIdx.x, tid = threadIdx.x;  // 512 threads
  hb[tid] = 0.5f * (hidden[b * 512 + tid] + hidden[32768 + b * 512 + tid]);
  __syncthreads();
  const f32x4* wr = (const f32x4*)(Wh + tid * 512);
  const f32x4* hv = (const f32x4*)hb;
  float s = 0.f;
  for (int k = 0; k < 128; ++k) {
    f32x4 w = wr[k], x = hv[k];
    s += w.x * x.x + w.y * x.y + w.z * x.z + w.w * x.w;
  }
  comb[b * 512 + tid] = s + bh[tid] + be[tid];
}

// ---------------- prep 2: pack We -> bf16 quarter-panel LDS images; zero scores
// Quarter q, col c (0..127), k-octet g (0..63): granule (16B, 8 bf16 of
// We[q*128+c][g*8..+8]) stored at granule index (within quarter):
//   (g>>1)*256 + (c>>5)*64 + (g&1)*32 + (c&31)
// so that in the GEMM, iter kk / col-tile ct reads lanes at
//   kk*4096 + ct*1024 + lane*16   -- perfectly contiguous 1024 B per ds_read.
__global__ void prep_pack_kernel(const float* __restrict__ We,
                                 unsigned short* __restrict__ wsw,
                                 float* __restrict__ scores) {
  const int gid = blockIdx.x * 256 + threadIdx.x;  // 0..32767
  const int q = gid >> 13;
  const int rem = gid & 8191;
  const int c = rem >> 6;
  const int g = rem & 63;
  const float* src = We + (q * 128 + c) * 512 + g * 8;
  u16x8 p;
#pragma unroll
  for (int e = 0; e < 8; ++e)
    p[e] = __builtin_bit_cast(unsigned short, (__bf16)src[e]);
  const int dgran = q * 8192 + (g >> 1) * 256 + (c >> 5) * 64 + (g & 1) * 32 + (c & 31);
  *(u16x8*)(wsw + (long)dgran * 8) = p;
  // zero scores (131072 f32 / 32768 threads = 1 f32x4 each)
  ((f32x4*)scores)[gid] = (f32x4){0.f, 0.f, 0.f, 0.f};
}

// ---------------- main: streaming fused GEMM + tanh + Wo-dot -> scores -------
// grid 1024: bid -> (quarter q, mchunk of 512 rows); 4 quarters of one mchunk
// land on the same XCD (bid&7) and adjacent in dispatch for L2 reuse of A.
// 512 threads = 8 waves; each wave: 2 strips of 32 rows, 32 K-iters each,
// mfma_f32_32x32x16_bf16, acc 4 tiles x f32x16. No barriers after B-stage.
__global__ __launch_bounds__(512, 2) void gemm_score_kernel(
    const float* __restrict__ enc,            // [131072, 512] (row = t*64+b)
    const unsigned short* __restrict__ wsw,   // packed We quarter panels
    const float* __restrict__ comb,           // [64,512]
    const float* __restrict__ Wo,             // [512]
    float* __restrict__ scores)               // [64,2048] (atomic partial sums)
{
  __shared__ __align__(16) unsigned char Blds[131072];  // [kk 32][ct 4][h 2][c31 32] granules

  const int tid = threadIdx.x;
  const int lane = tid & 63;
  const int wave = tid >> 6;
  const int bid = blockIdx.x;
  const int q = (bid >> 3) & 3;
  const int mchunk = (bid & 7) * 32 + (bid >> 5);   // [0,256)

  // stage B quarter panel: 512 thr x 16 B x 16 rounds = 128 KB, linear
  const unsigned char* bsrc = (const unsigned char*)wsw + (long)q * 131072 + tid * 16;
#pragma unroll
  for (int r = 0; r < 16; ++r)
    __builtin_amdgcn_global_load_lds((const AS1 unsigned int*)(bsrc + r * 8192),
                                     (AS3 unsigned int*)(&Blds[tid * 16 + r * 8192]),
                                     16, 0, 0);

  const int c31 = lane & 31;
  const int h = lane >> 5;
  float wo[4];
#pragma unroll
  for (int ct = 0; ct < 4; ++ct) wo[ct] = Wo[q * 128 + ct * 32 + c31];

  __syncthreads();  // single barrier: panel ready (drains glds)

  const unsigned bb = (unsigned)(h * 512 + c31 * 16);
  const long rowbase = (long)mchunk * 512 + wave * 64;

#pragma unroll 1
  for (int s = 0; s < 2; ++s) {
    const long r0 = rowbase + s * 32;
    // A frag source: lane -> row c31, k-half h: 8 consecutive f32 per iter
    const float* ag = enc + (r0 + c31) * 512 + h * 8;

    f32x16 acc0, acc1, acc2, acc3;
#pragma unroll
    for (int i = 0; i < 16; ++i) { acc0[i] = 0.f; acc1[i] = 0.f; acc2[i] = 0.f; acc3[i] = 0.f; }

    f32x4 ap[4][2];  // rolling 4-deep A prefetch (static idx via full unroll)
#pragma unroll
    for (int i = 0; i < 4; ++i) {
      ap[i][0] = *(const f32x4*)(ag + i * 16);
      ap[i][1] = *(const f32x4*)(ag + i * 16 + 4);
    }

#pragma unroll
    for (int kk = 0; kk < 32; ++kk) {
      f32x4 a0 = ap[kk & 3][0], a1 = ap[kk & 3][1];
      if (kk + 4 < 32) {
        ap[kk & 3][0] = *(const f32x4*)(ag + (kk + 4) * 16);
        ap[kk & 3][1] = *(const f32x4*)(ag + (kk + 4) * 16 + 4);
      }
      bf16x8 af;
      af[0] = (__bf16)a0.x; af[1] = (__bf16)a0.y; af[2] = (__bf16)a0.z; af[3] = (__bf16)a0.w;
      af[4] = (__bf16)a1.x; af[5] = (__bf16)a1.y; af[6] = (__bf16)a1.z; af[7] = (__bf16)a1.w;
      const unsigned kb = bb + (unsigned)kk * 4096;
      bf16x8 b0 = *(const bf16x8*)(&Blds[kb]);
      bf16x8 b1 = *(const bf16x8*)(&Blds[kb + 1024]);
      bf16x8 b2 = *(const bf16x8*)(&Blds[kb + 2048]);
      bf16x8 b3 = *(const bf16x8*)(&Blds[kb + 3072]);
      acc0 = __builtin_amdgcn_mfma_f32_32x32x16_bf16(af, b0, acc0, 0, 0, 0);
      acc1 = __builtin_amdgcn_mfma_f32_32x32x16_bf16(af, b1, acc1, 0, 0, 0);
      acc2 = __builtin_amdgcn_mfma_f32_32x32x16_bf16(af, b2, acc2, 0, 0, 0);
      acc3 = __builtin_amdgcn_mfma_f32_32x32x16_bf16(af, b3, acc3, 0, 0, 0);
    }

    // epilogue: D frag row = (r&3)+8*(r>>2)+4*h (r=0..15), col = ct*32+c31.
    // partial score = sum over this quarter's 128 cols of tanh(acc+comb)*Wo.
#pragma unroll
    for (int r = 0; r < 16; ++r) {
      const int row = (r & 3) + 8 * (r >> 2) + 4 * h;
      const long grow = r0 + row;
      const float* crow = comb + (int)(grow & 63) * 512 + q * 128;
      float sum = fast_tanh(acc0[r] + crow[c31]) * wo[0]
                + fast_tanh(acc1[r] + crow[32 + c31]) * wo[1]
                + fast_tanh(acc2[r] + crow[64 + c31]) * wo[2]
                + fast_tanh(acc3[r] + crow[96 + c31]) * wo[3];
      sum += __shfl_xor(sum, 1);
      sum += __shfl_xor(sum, 2);
      sum += __shfl_xor(sum, 4);
      sum += __shfl_xor(sum, 8);
      sum += __shfl_xor(sum, 16);  // stays within 32-lane half
      if (c31 == r)  // 2 lanes (h=0,1) -> different rows -> distinct addrs
        atomicAdd(scores + (grow & 63) * 2048 + (grow >> 6), sum);
    }
  }
}

// ---------------- masked softmax over valid prefix ---------------------------
__global__ void softmax_kernel(const float* __restrict__ scores,
                               const int* __restrict__ enc_len,
                               float* __restrict__ out) {
  const int b = blockIdx.x;
  const int tid = threadIdx.x;  // 256
  const int lane = tid & 63;
  const int wv = tid >> 6;
  __shared__ float red[4];
  const int n = enc_len[b];
  const float* sc = scores + (long)b * 2048;

  float v[8];
  float m = -1e30f;
#pragma unroll
  for (int j = 0; j < 8; ++j) {
    const int t = tid + j * 256;
    v[j] = sc[t];
    if (t < n) m = fmaxf(m, v[j]);
  }
#pragma unroll
  for (int k = 32; k; k >>= 1) m = fmaxf(m, __shfl_xor(m, k, 64));
  if (lane == 0) red[wv] = m;
  __syncthreads();
  m = fmaxf(fmaxf(red[0], red[1]), fmaxf(red[2], red[3]));
  __syncthreads();

  float s = 0.f;
#pragma unroll
  for (int j = 0; j < 8; ++j) {
    const int t = tid + j * 256;
    const float e = (t < n) ? __expf(v[j] - m) : 0.f;
    v[j] = e;
    s += e;
  }
#pragma unroll
  for (int k = 32; k; k >>= 1) s += __shfl_xor(s, k, 64);
  if (lane == 0) red[wv] = s;
  __syncthreads();
  s = red[0] + red[1] + red[2] + red[3];
  const float inv = 1.0f / s;
#pragma unroll
  for (int j = 0; j < 8; ++j) {
    const int t = tid + j * 256;
    out[(long)b * 2048 + t] = v[j] * inv;
  }
}

extern "C" void kernel_launch(void* const* d_in, const int* in_sizes, int n_in,
                              void* d_out, int out_size, void* d_ws, size_t ws_size,
                              hipStream_t stream) {
  const float* hidden = (const float*)d_in[0];   // [2,64,512]
  const float* enc    = (const float*)d_in[1];   // [2048,64,512]
  const int*   enclen = (const int*)d_in[2];     // [64]
  const float* Wh     = (const float*)d_in[3];   // [512,512]
  const float* bh     = (const float*)d_in[4];   // [512]
  const float* We     = (const float*)d_in[5];   // [512,512]
  const float* be     = (const float*)d_in[6];   // [512]
  const float* Wo     = (const float*)d_in[7];   // [512]
  // d_in[8] = bo: softmax-invariant, dropped
  float* out = (float*)d_out;

  uint8_t* ws = (uint8_t*)d_ws;
  unsigned short* wsw = (unsigned short*)ws;             // 512 KB packed We
  float* comb   = (float*)(ws + 524288);                 // 128 KB
  float* scores = (float*)(ws + 524288 + 131072);        // 512 KB

  hipLaunchKernelGGL(prep_comb_kernel, dim3(64), dim3(512), 0, stream,
                     hidden, Wh, bh, be, comb);
  hipLaunchKernelGGL(prep_pack_kernel, dim3(128), dim3(256), 0, stream,
                     We, wsw, scores);
  hipLaunchKernelGGL(gemm_score_kernel, dim3(1024), dim3(512), 0, stream,
                     enc, wsw, comb, Wo, scores);
  hipLaunchKernelGGL(softmax_kernel, dim3(64), dim3(256), 0, stream,
                     scores, enclen, out);
}

// Round 6
// 219.054 us; speedup vs baseline: 3.3657x; 3.3657x over previous
//
#include <hip/hip_runtime.h>
#include <stdint.h>

// Problem: BahdanauAttention  H=512, L=2, B=64, T=2048
// scores[t,b] = Wo . tanh( enc[t,b,:] @ We^T + comb[b,:] )   (bo dropped: softmax-invariant)
// comb[b,:]   = mean_l(hidden[l,b,:]) @ Wh^T + bh + be
// out[b,t]    = masked softmax over t < enc_len[b]
//
// R6: zero-LDS zero-barrier waveGEMM. Each wave owns 32 rows x full N=512.
// A: 32x512 f32 read ONCE -> bf16 frags in 64 VGPRs (af[2][16], static idx,
// 4-deep rolling f32 stage). Then 8 col-chunks of 64: B frags streamed direct
// from L2 (packed 1KB contiguous per frag, 3-deep prefetch), acc[2][4],
// fused tanh+Wo-dot epilogue into running s[2][4], plain stores. No atomics,
// no LDS, no barriers, no global_load_lds. VGPR ~160 @ launch_bounds(256,2).
//
// Workspace (1,152 KB):
//   [0, 512K)     : We packed bf16 frag-granules (see prep_pack)
//   [512K, 640K)  : comb_t f32 [512 col][64 b]  (transposed)
//   [640K, 1152K) : scores f32 [64][2048]

typedef __attribute__((ext_vector_type(4))) float f32x4;
typedef __attribute__((ext_vector_type(8))) __bf16 bf16x8;
typedef __attribute__((ext_vector_type(8))) unsigned short u16x8;

__device__ __forceinline__ float fast_tanh(float x) {
  float t = __expf(-2.0f * __builtin_fabsf(x));
  float r = (1.0f - t) * __builtin_amdgcn_rcpf(1.0f + t);
  return __builtin_copysignf(r, x);
}

// ---------------- prep 1: comb_t[o][b] = (mean_l hidden @ Wh^T + bh + be)^T --
__global__ void prep_comb_kernel(const float* __restrict__ hidden,
                                 const float* __restrict__ Wh,
                                 const float* __restrict__ bh,
                                 const float* __restrict__ be,
                                 float* __restrict__ comb_t) {
  __shared__ float hb[512];
  const int b = blockIdx.x, tid = threadIdx.x;  // 512 threads, tid = o
  hb[tid] = 0.5f * (hidden[b * 512 + tid] + hidden[32768 + b * 512 + tid]);
  __syncthreads();
  const f32x4* wr = (const f32x4*)(Wh + tid * 512);
  const f32x4* hv = (const f32x4*)hb;
  float s = 0.f;
  for (int k = 0; k < 128; ++k) {
    f32x4 w = wr[k], x = hv[k];
    s += w.x * x.x + w.y * x.y + w.z * x.z + w.w * x.w;
  }
  comb_t[tid * 64 + b] = s + bh[tid] + be[tid];
}

// ---------------- prep 2: pack We -> bf16 B-fragment granules ----------------
// Granule gid (16 B = 8 bf16): lane = gid&63, nt = (gid>>6)&3, kh = (gid>>8)&15,
// nh = gid>>12 (0..7).  col = nh*64 + nt*16 + (lane&15), k = kh*32 + (lane>>4)*8.
// Content = bf16(We[col][k..k+8]). A wave's frag load (fixed nh,kh,nt) is one
// contiguous 1 KB global_load_dwordx4.
__global__ void prep_pack_kernel(const float* __restrict__ We,
                                 unsigned short* __restrict__ wsw) {
  const int gid = blockIdx.x * 256 + threadIdx.x;  // 0..32767
  const int lane = gid & 63;
  const int nt = (gid >> 6) & 3;
  const int kh = (gid >> 8) & 15;
  const int nh = gid >> 12;
  const int col = nh * 64 + nt * 16 + (lane & 15);
  const int k = kh * 32 + (lane >> 4) * 8;
  const float* src = We + col * 512 + k;
  u16x8 p;
#pragma unroll
  for (int e = 0; e < 8; ++e)
    p[e] = __builtin_bit_cast(unsigned short, (__bf16)src[e]);
  *(u16x8*)(wsw + (long)gid * 8) = p;
}

// ---------------- main: per-wave streaming GEMM + tanh + Wo-dot --------------
// grid 1024 x 256 thr (4 waves). wave widx = bid*4+w owns rows [widx*32, +32):
// t = widx>>1, b-half = (widx&1)*32. No inter-thread communication except
// width-16 shuffles at the end.
__global__ __launch_bounds__(256, 2) void gemm_score_kernel(
    const float* __restrict__ enc,            // [131072, 512] (row = t*64+b)
    const unsigned short* __restrict__ wsw,   // packed We frags
    const float* __restrict__ comb_t,         // [512][64]
    const float* __restrict__ Wo,             // [512]
    float* __restrict__ scores)               // [64][2048]
{
  const int tid = threadIdx.x;
  const int lane = tid & 63;
  const int l15 = lane & 15;
  const int lq = lane >> 4;
  const int widx = blockIdx.x * 4 + (tid >> 6);
  const long r0 = (long)widx * 32;
  const int bhalf = (widx & 1) * 32;
  const long t = widx >> 1;

  // ---- phase 1: A (32 rows x 512 K) -> bf16 frags in regs, read once ----
  // af[m][kh]: 8 bf16 of row (r0 + m*16 + l15), k = kh*32 + lq*8
  bf16x8 af[2][16];
  const float* ab = enc + (r0 + l15) * 512 + lq * 8;

  f32x4 st[4][2][2];  // 4-deep kh pipeline x m x (lo,hi); static idx via unroll
#pragma unroll
  for (int i = 0; i < 4; ++i)
#pragma unroll
    for (int m = 0; m < 2; ++m) {
      st[i][m][0] = *(const f32x4*)(ab + m * 8192 + i * 32);
      st[i][m][1] = *(const f32x4*)(ab + m * 8192 + i * 32 + 4);
    }
#pragma unroll
  for (int kh = 0; kh < 16; ++kh) {
#pragma unroll
    for (int m = 0; m < 2; ++m) {
      f32x4 lo = st[kh & 3][m][0], hi = st[kh & 3][m][1];
      if (kh + 4 < 16) {
        st[kh & 3][m][0] = *(const f32x4*)(ab + m * 8192 + (kh + 4) * 32);
        st[kh & 3][m][1] = *(const f32x4*)(ab + m * 8192 + (kh + 4) * 32 + 4);
      }
      bf16x8 v;
      v[0] = (__bf16)lo.x; v[1] = (__bf16)lo.y; v[2] = (__bf16)lo.z; v[3] = (__bf16)lo.w;
      v[4] = (__bf16)hi.x; v[5] = (__bf16)hi.y; v[6] = (__bf16)hi.z; v[7] = (__bf16)hi.w;
      af[m][kh] = v;
    }
  }

  // ---- phase 2: 8 col-chunks of 64; B frags direct from L2, 3-deep prefetch --
  float s_acc[2][4];
#pragma unroll
  for (int m = 0; m < 2; ++m)
#pragma unroll
    for (int q = 0; q < 4; ++q) s_acc[m][q] = 0.f;

#pragma unroll 1
  for (int nh = 0; nh < 8; ++nh) {
    // granule base for this nh; frag (kh,nt) at shorts offset kh*2048+nt*512+lane*8
    const unsigned short* bb = wsw + (long)nh * 32768 + lane * 8;

    bf16x8 bp0[4], bp1[4], bp2[4];
#pragma unroll
    for (int nt = 0; nt < 4; ++nt) {
      bp0[nt] = *(const bf16x8*)(bb + 0 * 2048 + nt * 512);
      bp1[nt] = *(const bf16x8*)(bb + 1 * 2048 + nt * 512);
      bp2[nt] = *(const bf16x8*)(bb + 2 * 2048 + nt * 512);
    }

    f32x4 acc[2][4];
#pragma unroll
    for (int m = 0; m < 2; ++m)
#pragma unroll
      for (int nt = 0; nt < 4; ++nt) acc[m][nt] = (f32x4){0.f, 0.f, 0.f, 0.f};

#define KH_STEP(kh, BP)                                                        \
  {                                                                            \
    _Pragma("unroll")                                                          \
    for (int nt = 0; nt < 4; ++nt) {                                           \
      acc[0][nt] = __builtin_amdgcn_mfma_f32_16x16x32_bf16(af[0][kh], BP[nt],  \
                                                           acc[0][nt], 0, 0, 0); \
      acc[1][nt] = __builtin_amdgcn_mfma_f32_16x16x32_bf16(af[1][kh], BP[nt],  \
                                                           acc[1][nt], 0, 0, 0); \
    }                                                                          \
    if ((kh) + 3 < 16) {                                                       \
      _Pragma("unroll")                                                        \
      for (int nt = 0; nt < 4; ++nt)                                           \
        BP[nt] = *(const bf16x8*)(bb + ((kh) + 3) * 2048 + nt * 512);          \
    }                                                                          \
  }

    KH_STEP(0, bp0)  KH_STEP(1, bp1)  KH_STEP(2, bp2)  KH_STEP(3, bp0)
    KH_STEP(4, bp1)  KH_STEP(5, bp2)  KH_STEP(6, bp0)  KH_STEP(7, bp1)
    KH_STEP(8, bp2)  KH_STEP(9, bp0)  KH_STEP(10, bp1) KH_STEP(11, bp2)
    KH_STEP(12, bp0) KH_STEP(13, bp1) KH_STEP(14, bp2) KH_STEP(15, bp0)
#undef KH_STEP

    // epilogue for this col-chunk: s += tanh(acc + comb)*Wo
    float wo[4];
#pragma unroll
    for (int nt = 0; nt < 4; ++nt) wo[nt] = Wo[nh * 64 + nt * 16 + l15];
    const float* ct = comb_t + (nh * 64 + l15) * 64 + bhalf + lq * 4;
#pragma unroll
    for (int m = 0; m < 2; ++m)
#pragma unroll
      for (int q = 0; q < 4; ++q) {
        float sm = 0.f;
#pragma unroll
        for (int nt = 0; nt < 4; ++nt) {
          const float x = acc[m][nt][q] + ct[nt * 1024 + m * 16 + q];
          sm += fast_tanh(x) * wo[nt];
        }
        s_acc[m][q] += sm;
      }
  }

  // ---- reduce over l15 (16 lanes share a row-group) and store ----
#pragma unroll
  for (int m = 0; m < 2; ++m)
#pragma unroll
    for (int q = 0; q < 4; ++q) {
      float v = s_acc[m][q];
      v += __shfl_xor(v, 1, 16);
      v += __shfl_xor(v, 2, 16);
      v += __shfl_xor(v, 4, 16);
      v += __shfl_xor(v, 8, 16);
      if (l15 == 0) {
        const int b = bhalf + m * 16 + lq * 4 + q;
        scores[(long)b * 2048 + t] = v;
      }
    }
}

// ---------------- masked softmax over valid prefix ---------------------------
__global__ void softmax_kernel(const float* __restrict__ scores,
                               const int* __restrict__ enc_len,
                               float* __restrict__ out) {
  const int b = blockIdx.x;
  const int tid = threadIdx.x;  // 256
  const int lane = tid & 63;
  const int wv = tid >> 6;
  __shared__ float red[4];
  const int n = enc_len[b];
  const float* sc = scores + (long)b * 2048;

  float v[8];
  float m = -1e30f;
#pragma unroll
  for (int j = 0; j < 8; ++j) {
    const int t = tid + j * 256;
    v[j] = sc[t];
    if (t < n) m = fmaxf(m, v[j]);
  }
#pragma unroll
  for (int k = 32; k; k >>= 1) m = fmaxf(m, __shfl_xor(m, k, 64));
  if (lane == 0) red[wv] = m;
  __syncthreads();
  m = fmaxf(fmaxf(red[0], red[1]), fmaxf(red[2], red[3]));
  __syncthreads();

  float s = 0.f;
#pragma unroll
  for (int j = 0; j < 8; ++j) {
    const int t = tid + j * 256;
    const float e = (t < n) ? __expf(v[j] - m) : 0.f;
    v[j] = e;
    s += e;
  }
#pragma unroll
  for (int k = 32; k; k >>= 1) s += __shfl_xor(s, k, 64);
  if (lane == 0) red[wv] = s;
  __syncthreads();
  s = red[0] + red[1] + red[2] + red[3];
  const float inv = 1.0f / s;
#pragma unroll
  for (int j = 0; j < 8; ++j) {
    const int t = tid + j * 256;
    out[(long)b * 2048 + t] = v[j] * inv;
  }
}

extern "C" void kernel_launch(void* const* d_in, const int* in_sizes, int n_in,
                              void* d_out, int out_size, void* d_ws, size_t ws_size,
                              hipStream_t stream) {
  const float* hidden = (const float*)d_in[0];   // [2,64,512]
  const float* enc    = (const float*)d_in[1];   // [2048,64,512]
  const int*   enclen = (const int*)d_in[2];     // [64]
  const float* Wh     = (const float*)d_in[3];   // [512,512]
  const float* bh     = (const float*)d_in[4];   // [512]
  const float* We     = (const float*)d_in[5];   // [512,512]
  const float* be     = (const float*)d_in[6];   // [512]
  const float* Wo     = (const float*)d_in[7];   // [512]
  // d_in[8] = bo: softmax-invariant, dropped
  float* out = (float*)d_out;

  uint8_t* ws = (uint8_t*)d_ws;
  unsigned short* wsw = (unsigned short*)ws;             // 512 KB packed We
  float* comb_t = (float*)(ws + 524288);                 // 128 KB [512][64]
  float* scores = (float*)(ws + 524288 + 131072);        // 512 KB

  hipLaunchKernelGGL(prep_comb_kernel, dim3(64), dim3(512), 0, stream,
                     hidden, Wh, bh, be, comb_t);
  hipLaunchKernelGGL(prep_pack_kernel, dim3(128), dim3(256), 0, stream, We, wsw);
  hipLaunchKernelGGL(gemm_score_kernel, dim3(1024), dim3(256), 0, stream,
                     enc, wsw, comb_t, Wo, scores);
  hipLaunchKernelGGL(softmax_kernel, dim3(64), dim3(256), 0, stream,
                     scores, enclen, out);
}